// Round 1
// baseline (453.488 us; speedup 1.0000x reference)
//
#include <hip/hip_runtime.h>
#include <math.h>

#define N_SQ 64
#define TRUNCF 0.1f
#define EPSF 1e-6f

__global__ __launch_bounds__(256) void superq_kernel(
    const float* __restrict__ raw_scale,
    const float* __restrict__ raw_exp,
    const float* __restrict__ raw_rot,
    const float* __restrict__ trans,
    const float* __restrict__ points,
    float* __restrict__ out_sdf,
    float* __restrict__ out_nrm,
    int n_pts)
{
    // Per-SQ parameters staged in LDS (SoA layout; reads below are wave-uniform broadcasts).
    __shared__ float sR[9][N_SQ];
    __shared__ float sT[3][N_SQ];
    __shared__ float sS[3][N_SQ];    // scale (divide per reference op order)
    __shared__ float sIE1[N_SQ];     // 1/e1
    __shared__ float sIE2[N_SQ];     // 1/e2
    __shared__ float sM[N_SQ];       // e2/e1
    __shared__ float sNH[N_SQ];      // -e1/2

    const int tid = threadIdx.x;
    if (tid < N_SQ) {
        const int j = tid;
        // quat2mat with normalization, q = (w,x,y,z)
        float qw = raw_rot[j * 4 + 0], qx = raw_rot[j * 4 + 1];
        float qy = raw_rot[j * 4 + 2], qz = raw_rot[j * 4 + 3];
        float qn = sqrtf(qw * qw + qx * qx + qy * qy + qz * qz);
        qw /= qn; qx /= qn; qy /= qn; qz /= qn;
        sR[0][j] = 1.f - 2.f * (qy * qy + qz * qz);
        sR[1][j] = 2.f * (qx * qy - qw * qz);
        sR[2][j] = 2.f * (qx * qz + qw * qy);
        sR[3][j] = 2.f * (qx * qy + qw * qz);
        sR[4][j] = 1.f - 2.f * (qx * qx + qz * qz);
        sR[5][j] = 2.f * (qy * qz - qw * qx);
        sR[6][j] = 2.f * (qx * qz - qw * qy);
        sR[7][j] = 2.f * (qy * qz + qw * qx);
        sR[8][j] = 1.f - 2.f * (qx * qx + qy * qy);
        sT[0][j] = trans[j * 3 + 0];
        sT[1][j] = trans[j * 3 + 1];
        sT[2][j] = trans[j * 3 + 2];
        sS[0][j] = expf(raw_scale[j * 3 + 0]);
        sS[1][j] = expf(raw_scale[j * 3 + 1]);
        sS[2][j] = expf(raw_scale[j * 3 + 2]);
        float e1 = 1.f / (1.f + expf(-raw_exp[j * 2 + 0])) * 1.8f + 0.1f;
        float e2 = 1.f / (1.f + expf(-raw_exp[j * 2 + 1])) * 1.8f + 0.1f;
        sIE1[j] = 1.f / e1;
        sIE2[j] = 1.f / e2;
        sM[j]   = e2 / e1;
        sNH[j]  = -e1 * 0.5f;   // == -e1/2.0 exactly
    }
    __syncthreads();

    const int p = blockIdx.x * blockDim.x + tid;
    if (p >= n_pts) return;

    const float px = points[p * 3 + 0];
    const float py = points[p * 3 + 1];
    const float pz = points[p * 3 + 2];

    float best = INFINITY;
    float bnx = 0.f, bny = 0.f, bnz = 0.f;

    for (int j = 0; j < N_SQ; ++j) {
        const float R00 = sR[0][j], R01 = sR[1][j], R02 = sR[2][j];
        const float R10 = sR[3][j], R11 = sR[4][j], R12 = sR[5][j];
        const float R20 = sR[6][j], R21 = sR[7][j], R22 = sR[8][j];
        const float ux = px - sT[0][j];
        const float uy = py - sT[1][j];
        const float uz = pz - sT[2][j];
        // Xc = R^T u
        const float X0 = R00 * ux + R10 * uy + R20 * uz;
        const float X1 = R01 * ux + R11 * uy + R21 * uz;
        const float X2 = R02 * ux + R12 * uy + R22 * uz;
        // sgn per reference: (Xc > 0) ? 1 : -1
        const float s0 = X0 > 0.f ? 1.f : -1.f;
        const float s1 = X1 > 0.f ? 1.f : -1.f;
        const float s2 = X2 > 0.f ? 1.f : -1.f;
        const float a0 = fabsf(X0), a1 = fabsf(X1), a2 = fabsf(X2);
        const float x = s0 * fmaxf(a0, EPSF);
        const float y = s1 * fmaxf(a1, EPSF);
        const float z = s2 * fmaxf(a2, EPSF);
        // d(clamp)/dXc mask
        const float m0 = a0 > EPSF ? 1.f : 0.f;
        const float m1 = a1 > EPSF ? 1.f : 0.f;
        const float m2 = a2 > EPSF ? 1.f : 0.f;

        const float r0 = sqrtf(x * x + y * y + z * z);

        const float ie1 = sIE1[j], ie2 = sIE2[j], mm = sM[j], nh = sNH[j];
        const float xs = x / sS[0][j];
        const float ys = y / sS[1][j];
        const float zs = z / sS[2][j];
        const float t1 = powf(xs * xs, ie2);
        const float t2 = powf(ys * ys, ie2);
        const float t3 = powf(zs * zs, ie1);
        const float A = t1 + t2 + EPSF;
        const float B = powf(A, mm);
        const float S = B + t3;
        const float f = powf(S, nh);
        const float sdf = r0 * (1.f - f);

        // Analytic gradient wrt X (then mask, then rotate to p-space):
        // dsdf/dx = (x/r0)(1-f) + r0*f*B*t1/(S*A*x)
        // dsdf/dy = (y/r0)(1-f) + r0*f*B*t2/(S*A*y)
        // dsdf/dz = (z/r0)(1-f) + r0*f*t3/(S*z)
        const float omf = 1.f - f;
        const float c1 = omf / r0;
        const float w = r0 * f / S;
        const float wBA = w * B / A;
        float gx = c1 * x + wBA * t1 / x;
        float gy = c1 * y + wBA * t2 / y;
        float gz = c1 * z + w * t3 / z;
        gx *= m0; gy *= m1; gz *= m2;
        // g_p = R * g_Xc
        const float gpx = R00 * gx + R01 * gy + R02 * gz;
        const float gpy = R10 * gx + R11 * gy + R12 * gz;
        const float gpz = R20 * gx + R21 * gy + R22 * gz;
        const float nrm = sqrtf(gpx * gpx + gpy * gpy + gpz * gpz);
        const float inv_n = 1.f / fmaxf(nrm, 1e-12f);
        const float nx = gpx * inv_n;
        const float ny = gpy * inv_n;
        const float nz = gpz * inv_n;

        // truncation BEFORE the min-reduce (reference clips sdf_all first)
        const float sdfc = fminf(fmaxf(sdf, -TRUNCF), TRUNCF);

        // first-min-wins (strict <) to replicate jnp.argmin tie-breaking
        if (sdfc < best) {
            best = sdfc;
            bnx = nx; bny = ny; bnz = nz;
        }
    }

    out_sdf[p] = best;
    out_nrm[p * 3 + 0] = bnx;
    out_nrm[p * 3 + 1] = bny;
    out_nrm[p * 3 + 2] = bnz;
}

extern "C" void kernel_launch(void* const* d_in, const int* in_sizes, int n_in,
                              void* d_out, int out_size, void* d_ws, size_t ws_size,
                              hipStream_t stream) {
    const float* raw_scale = (const float*)d_in[0];
    const float* raw_exp   = (const float*)d_in[1];
    const float* raw_rot   = (const float*)d_in[2];
    const float* trans     = (const float*)d_in[3];
    const float* points    = (const float*)d_in[4];
    float* out = (float*)d_out;

    const int n_pts = in_sizes[4] / 3;
    float* out_sdf = out;            // [n_pts]
    float* out_nrm = out + n_pts;    // [n_pts, 3]

    const int block = 256;
    const int grid = (n_pts + block - 1) / block;
    superq_kernel<<<grid, block, 0, stream>>>(raw_scale, raw_exp, raw_rot, trans,
                                              points, out_sdf, out_nrm, n_pts);
}

// Round 2
// 111.838 us; speedup vs baseline: 4.0549x; 4.0549x over previous
//
#include <hip/hip_runtime.h>
#include <math.h>

#define N_SQ 64
#define TRUNCF 0.1f
#define EPSF 1e-6f

// --- fast hardware transcendentals (bases are guaranteed > 0 here) ---
__device__ __forceinline__ float flog2(float x) {
#if __has_builtin(__builtin_amdgcn_logf)
    return __builtin_amdgcn_logf(x);        // v_log_f32
#else
    return __log2f(x);
#endif
}
__device__ __forceinline__ float fexp2(float x) {
#if __has_builtin(__builtin_amdgcn_exp2f)
    return __builtin_amdgcn_exp2f(x);       // v_exp_f32
#else
    return exp2f(x);
#endif
}
__device__ __forceinline__ float frcp(float x)  { return __builtin_amdgcn_rcpf(x); }  // v_rcp_f32
__device__ __forceinline__ float frsq(float x)  { return __builtin_amdgcn_rsqf(x); }  // v_rsq_f32

__global__ __launch_bounds__(256) void superq_kernel(
    const float* __restrict__ raw_scale,
    const float* __restrict__ raw_exp,
    const float* __restrict__ raw_rot,
    const float* __restrict__ trans,
    const float* __restrict__ points,
    float* __restrict__ out_sdf,
    float* __restrict__ out_nrm,
    int n_pts)
{
    // Per-SQ params packed as 5 x float4 (80 B/SQ, 16B-aligned) so the hot
    // loop does 5 ds_read_b128 (uniform index -> broadcast, no conflicts)
    // instead of 19 ds_read_b32.
    //  [0] = R00,R01,R02,T0
    //  [1] = R10,R11,R12,T1
    //  [2] = R20,R21,R22,T2
    //  [3] = iSx,iSy,iSz,c2e2   (c2e2 = 2/e2)
    //  [4] = c2e1, mm, nh, 0    (c2e1 = 2/e1, mm = e2/e1, nh = -e1/2)
    __shared__ float4 sP[N_SQ][5];

    const int tid = threadIdx.x;
    if (tid < N_SQ) {
        const int j = tid;
        float qw = raw_rot[j * 4 + 0], qx = raw_rot[j * 4 + 1];
        float qy = raw_rot[j * 4 + 2], qz = raw_rot[j * 4 + 3];
        float qn = sqrtf(qw * qw + qx * qx + qy * qy + qz * qz);
        qw /= qn; qx /= qn; qy /= qn; qz /= qn;
        const float R00 = 1.f - 2.f * (qy * qy + qz * qz);
        const float R01 = 2.f * (qx * qy - qw * qz);
        const float R02 = 2.f * (qx * qz + qw * qy);
        const float R10 = 2.f * (qx * qy + qw * qz);
        const float R11 = 1.f - 2.f * (qx * qx + qz * qz);
        const float R12 = 2.f * (qy * qz - qw * qx);
        const float R20 = 2.f * (qx * qz - qw * qy);
        const float R21 = 2.f * (qy * qz + qw * qx);
        const float R22 = 1.f - 2.f * (qx * qx + qy * qy);
        const float e1 = 1.f / (1.f + expf(-raw_exp[j * 2 + 0])) * 1.8f + 0.1f;
        const float e2 = 1.f / (1.f + expf(-raw_exp[j * 2 + 1])) * 1.8f + 0.1f;
        sP[j][0] = make_float4(R00, R01, R02, trans[j * 3 + 0]);
        sP[j][1] = make_float4(R10, R11, R12, trans[j * 3 + 1]);
        sP[j][2] = make_float4(R20, R21, R22, trans[j * 3 + 2]);
        sP[j][3] = make_float4(expf(-raw_scale[j * 3 + 0]),
                               expf(-raw_scale[j * 3 + 1]),
                               expf(-raw_scale[j * 3 + 2]),
                               2.f / e2);
        sP[j][4] = make_float4(2.f / e1, e2 / e1, -e1 * 0.5f, 0.f);
    }
    __syncthreads();

    const int p = blockIdx.x * blockDim.x + tid;
    if (p >= n_pts) return;

    const float px = points[p * 3 + 0];
    const float py = points[p * 3 + 1];
    const float pz = points[p * 3 + 2];

    float best = INFINITY;
    float bgx = 0.f, bgy = 0.f, bgz = 0.f;   // best *unnormalized* gradient

    #pragma unroll 2
    for (int j = 0; j < N_SQ; ++j) {
        const float4 r0v = sP[j][0];
        const float4 r1v = sP[j][1];
        const float4 r2v = sP[j][2];
        const float4 sc  = sP[j][3];
        const float4 ex  = sP[j][4];

        const float ux = px - r0v.w;
        const float uy = py - r1v.w;
        const float uz = pz - r2v.w;
        // Xc = R^T u (columns of R)
        const float X0 = r0v.x * ux + r1v.x * uy + r2v.x * uz;
        const float X1 = r0v.y * ux + r1v.y * uy + r2v.y * uz;
        const float X2 = r0v.z * ux + r1v.z * uy + r2v.z * uz;

        const float a0 = fabsf(X0), a1 = fabsf(X1), a2 = fabsf(X2);
        const float ax = fmaxf(a0, EPSF);
        const float ay = fmaxf(a1, EPSF);
        const float az = fmaxf(a2, EPSF);
        // combined sign * clamp-mask (gradient is odd in each coord)
        const float sm0 = (a0 > EPSF) ? ((X0 > 0.f) ? 1.f : -1.f) : 0.f;
        const float sm1 = (a1 > EPSF) ? ((X1 > 0.f) ? 1.f : -1.f) : 0.f;
        const float sm2 = (a2 > EPSF) ? ((X2 > 0.f) ? 1.f : -1.f) : 0.f;

        const float r2 = ax * ax + ay * ay + az * az;
        const float inv_r0 = frsq(r2);
        const float r0 = r2 * inv_r0;

        // t1 = ((x/sx)^2)^(1/e2) = exp2( (2/e2) * log2(ax * iSx) ), base > 0
        const float t1 = fexp2(sc.w * flog2(ax * sc.x));
        const float t2 = fexp2(sc.w * flog2(ay * sc.y));
        const float t3 = fexp2(ex.x * flog2(az * sc.z));

        const float A = t1 + t2 + EPSF;
        const float B = fexp2(ex.y * flog2(A));
        const float S = B + t3;
        const float f = fexp2(ex.z * flog2(S));

        const float omf = 1.f - f;
        const float sdf = r0 * omf;
        const float c1  = omf * inv_r0;
        const float w   = r0 * f * frcp(S);
        const float wBA = w * B * frcp(A);

        // odd-symmetric gradient magnitudes (computed with |coords|)
        const float gmx = fmaf(wBA * t1, frcp(ax), c1 * ax);
        const float gmy = fmaf(wBA * t2, frcp(ay), c1 * ay);
        const float gmz = fmaf(w  * t3, frcp(az), c1 * az);
        const float gx = gmx * sm0;
        const float gy = gmy * sm1;
        const float gz = gmz * sm2;
        // g_p = R * g
        const float gpx = r0v.x * gx + r0v.y * gy + r0v.z * gz;
        const float gpy = r1v.x * gx + r1v.y * gy + r1v.z * gz;
        const float gpz = r2v.x * gx + r2v.y * gy + r2v.z * gz;

        // truncate BEFORE min-reduce; strict < = first-min-wins (ref argmin)
        const float sdfc = fminf(fmaxf(sdf, -TRUNCF), TRUNCF);
        const bool take = sdfc < best;
        best = take ? sdfc : best;
        bgx = take ? gpx : bgx;
        bgy = take ? gpy : bgy;
        bgz = take ? gpz : bgz;
    }

    // normalize once (selection never depended on normalization)
    const float n2 = bgx * bgx + bgy * bgy + bgz * bgz;
    const float inv_n = frsq(fmaxf(n2, 1e-24f));   // == 1/max(||g||,1e-12)

    out_sdf[p] = best;
    out_nrm[p * 3 + 0] = bgx * inv_n;
    out_nrm[p * 3 + 1] = bgy * inv_n;
    out_nrm[p * 3 + 2] = bgz * inv_n;
}

extern "C" void kernel_launch(void* const* d_in, const int* in_sizes, int n_in,
                              void* d_out, int out_size, void* d_ws, size_t ws_size,
                              hipStream_t stream) {
    const float* raw_scale = (const float*)d_in[0];
    const float* raw_exp   = (const float*)d_in[1];
    const float* raw_rot   = (const float*)d_in[2];
    const float* trans     = (const float*)d_in[3];
    const float* points    = (const float*)d_in[4];
    float* out = (float*)d_out;

    const int n_pts = in_sizes[4] / 3;
    float* out_sdf = out;            // [n_pts]
    float* out_nrm = out + n_pts;    // [n_pts, 3]

    const int block = 256;
    const int grid = (n_pts + block - 1) / block;
    superq_kernel<<<grid, block, 0, stream>>>(raw_scale, raw_exp, raw_rot, trans,
                                              points, out_sdf, out_nrm, n_pts);
}

// Round 3
// 94.450 us; speedup vs baseline: 4.8014x; 1.1841x over previous
//
#include <hip/hip_runtime.h>
#include <math.h>

#define N_SQ 64
#define TRUNCF 0.1f
#define EPSF 1e-6f

// --- fast hardware transcendentals (bases are guaranteed > 0 where used) ---
__device__ __forceinline__ float flog2(float x) { return __builtin_amdgcn_logf(x); }   // v_log_f32
__device__ __forceinline__ float fexp2(float x) { return __builtin_amdgcn_exp2f(x); }  // v_exp_f32
__device__ __forceinline__ float frcp(float x)  { return __builtin_amdgcn_rcpf(x); }   // v_rcp_f32
__device__ __forceinline__ float frsq(float x)  { return __builtin_amdgcn_rsqf(x); }   // v_rsq_f32

// Derived per-SQ parameter block: 5 x float4 (80 B), written to d_ws by prep_kernel.
//  [0] = R00,R01,R02,T0
//  [1] = R10,R11,R12,T1
//  [2] = R20,R21,R22,T2
//  [3] = iSx,iSy,iSz,c2e2   (c2e2 = 2/e2)
//  [4] = c2e1, mm, nh, 0    (c2e1 = 2/e1, mm = e2/e1, nh = -e1/2)
__global__ __launch_bounds__(64) void prep_kernel(
    const float* __restrict__ raw_scale,
    const float* __restrict__ raw_exp,
    const float* __restrict__ raw_rot,
    const float* __restrict__ trans,
    float4* __restrict__ params)
{
    const int j = threadIdx.x;
    if (j >= N_SQ) return;
    float qw = raw_rot[j * 4 + 0], qx = raw_rot[j * 4 + 1];
    float qy = raw_rot[j * 4 + 2], qz = raw_rot[j * 4 + 3];
    const float qn = sqrtf(qw * qw + qx * qx + qy * qy + qz * qz);
    qw /= qn; qx /= qn; qy /= qn; qz /= qn;
    const float e1 = 1.f / (1.f + expf(-raw_exp[j * 2 + 0])) * 1.8f + 0.1f;
    const float e2 = 1.f / (1.f + expf(-raw_exp[j * 2 + 1])) * 1.8f + 0.1f;
    params[j * 5 + 0] = make_float4(1.f - 2.f * (qy * qy + qz * qz),
                                    2.f * (qx * qy - qw * qz),
                                    2.f * (qx * qz + qw * qy),
                                    trans[j * 3 + 0]);
    params[j * 5 + 1] = make_float4(2.f * (qx * qy + qw * qz),
                                    1.f - 2.f * (qx * qx + qz * qz),
                                    2.f * (qy * qz - qw * qx),
                                    trans[j * 3 + 1]);
    params[j * 5 + 2] = make_float4(2.f * (qx * qz - qw * qy),
                                    2.f * (qy * qz + qw * qx),
                                    1.f - 2.f * (qx * qx + qy * qy),
                                    trans[j * 3 + 2]);
    params[j * 5 + 3] = make_float4(expf(-raw_scale[j * 3 + 0]),
                                    expf(-raw_scale[j * 3 + 1]),
                                    expf(-raw_scale[j * 3 + 2]),
                                    2.f / e2);
    params[j * 5 + 4] = make_float4(2.f / e1, e2 / e1, -e1 * 0.5f, 0.f);
}

__global__ __launch_bounds__(256) void superq_main(
    const float4* __restrict__ params,
    const float* __restrict__ points,
    float* __restrict__ out_sdf,
    float* __restrict__ out_nrm,
    int n_pts)
{
    const int p = blockIdx.x * blockDim.x + threadIdx.x;
    if (p >= n_pts) return;

    const float px = points[p * 3 + 0];
    const float py = points[p * 3 + 1];
    const float pz = points[p * 3 + 2];

    float best = INFINITY;
    int jb = 0;

    // Pass 1: sdf-only argmin. `j` is wave-uniform -> params[] loads become
    // scalar (SMEM) loads; no LDS, no gradient math in the hot loop.
    // Math is op-for-op identical to the round-2 kernel's sdf path.
    #pragma unroll 4
    for (int j = 0; j < N_SQ; ++j) {
        const float4 r0v = params[j * 5 + 0];
        const float4 r1v = params[j * 5 + 1];
        const float4 r2v = params[j * 5 + 2];
        const float4 sc  = params[j * 5 + 3];
        const float4 ex  = params[j * 5 + 4];

        const float ux = px - r0v.w;
        const float uy = py - r1v.w;
        const float uz = pz - r2v.w;
        const float X0 = r0v.x * ux + r1v.x * uy + r2v.x * uz;
        const float X1 = r0v.y * ux + r1v.y * uy + r2v.y * uz;
        const float X2 = r0v.z * ux + r1v.z * uy + r2v.z * uz;

        const float ax = fmaxf(fabsf(X0), EPSF);
        const float ay = fmaxf(fabsf(X1), EPSF);
        const float az = fmaxf(fabsf(X2), EPSF);

        const float r2 = ax * ax + ay * ay + az * az;
        const float inv_r0 = frsq(r2);
        const float r0 = r2 * inv_r0;

        const float t1 = fexp2(sc.w * flog2(ax * sc.x));
        const float t2 = fexp2(sc.w * flog2(ay * sc.y));
        const float t3 = fexp2(ex.x * flog2(az * sc.z));

        const float A = t1 + t2 + EPSF;
        const float B = fexp2(ex.y * flog2(A));
        const float S = B + t3;
        const float f = fexp2(ex.z * flog2(S));

        const float omf = 1.f - f;
        const float sdf = r0 * omf;
        const float sdfc = fminf(fmaxf(sdf, -TRUNCF), TRUNCF);

        const bool take = sdfc < best;   // strict < : first-min-wins (ref argmin)
        best = take ? sdfc : best;
        jb   = take ? j : jb;
    }

    // Pass 2: full gradient for the single winner (per-lane gather of params).
    // Identical op sequence to the round-2 kernel's gradient path.
    {
        const float4 r0v = params[jb * 5 + 0];
        const float4 r1v = params[jb * 5 + 1];
        const float4 r2v = params[jb * 5 + 2];
        const float4 sc  = params[jb * 5 + 3];
        const float4 ex  = params[jb * 5 + 4];

        const float ux = px - r0v.w;
        const float uy = py - r1v.w;
        const float uz = pz - r2v.w;
        const float X0 = r0v.x * ux + r1v.x * uy + r2v.x * uz;
        const float X1 = r0v.y * ux + r1v.y * uy + r2v.y * uz;
        const float X2 = r0v.z * ux + r1v.z * uy + r2v.z * uz;

        const float a0 = fabsf(X0), a1 = fabsf(X1), a2 = fabsf(X2);
        const float ax = fmaxf(a0, EPSF);
        const float ay = fmaxf(a1, EPSF);
        const float az = fmaxf(a2, EPSF);
        const float sm0 = (a0 > EPSF) ? ((X0 > 0.f) ? 1.f : -1.f) : 0.f;
        const float sm1 = (a1 > EPSF) ? ((X1 > 0.f) ? 1.f : -1.f) : 0.f;
        const float sm2 = (a2 > EPSF) ? ((X2 > 0.f) ? 1.f : -1.f) : 0.f;

        const float r2 = ax * ax + ay * ay + az * az;
        const float inv_r0 = frsq(r2);
        const float r0 = r2 * inv_r0;

        const float t1 = fexp2(sc.w * flog2(ax * sc.x));
        const float t2 = fexp2(sc.w * flog2(ay * sc.y));
        const float t3 = fexp2(ex.x * flog2(az * sc.z));

        const float A = t1 + t2 + EPSF;
        const float B = fexp2(ex.y * flog2(A));
        const float S = B + t3;
        const float f = fexp2(ex.z * flog2(S));

        const float omf = 1.f - f;
        const float c1  = omf * inv_r0;
        const float w   = r0 * f * frcp(S);
        const float wBA = w * B * frcp(A);

        const float gmx = fmaf(wBA * t1, frcp(ax), c1 * ax);
        const float gmy = fmaf(wBA * t2, frcp(ay), c1 * ay);
        const float gmz = fmaf(w  * t3, frcp(az), c1 * az);
        const float gx = gmx * sm0;
        const float gy = gmy * sm1;
        const float gz = gmz * sm2;
        const float gpx = r0v.x * gx + r0v.y * gy + r0v.z * gz;
        const float gpy = r1v.x * gx + r1v.y * gy + r1v.z * gz;
        const float gpz = r2v.x * gx + r2v.y * gy + r2v.z * gz;

        const float n2 = gpx * gpx + gpy * gpy + gpz * gpz;
        const float inv_n = frsq(fmaxf(n2, 1e-24f));   // == 1/max(||g||,1e-12)

        out_sdf[p] = best;
        out_nrm[p * 3 + 0] = gpx * inv_n;
        out_nrm[p * 3 + 1] = gpy * inv_n;
        out_nrm[p * 3 + 2] = gpz * inv_n;
    }
}

extern "C" void kernel_launch(void* const* d_in, const int* in_sizes, int n_in,
                              void* d_out, int out_size, void* d_ws, size_t ws_size,
                              hipStream_t stream) {
    const float* raw_scale = (const float*)d_in[0];
    const float* raw_exp   = (const float*)d_in[1];
    const float* raw_rot   = (const float*)d_in[2];
    const float* trans     = (const float*)d_in[3];
    const float* points    = (const float*)d_in[4];
    float* out = (float*)d_out;

    const int n_pts = in_sizes[4] / 3;
    float* out_sdf = out;            // [n_pts]
    float* out_nrm = out + n_pts;    // [n_pts, 3]

    float4* params = (float4*)d_ws;  // 64 * 5 * 16 B = 5120 B

    prep_kernel<<<1, 64, 0, stream>>>(raw_scale, raw_exp, raw_rot, trans, params);

    const int block = 256;
    const int grid = (n_pts + block - 1) / block;
    superq_main<<<grid, block, 0, stream>>>(params, points, out_sdf, out_nrm, n_pts);
}